// Round 1
// baseline (1725.799 us; speedup 1.0000x reference)
//
#include <hip/hip_runtime.h>
#include <math.h>

// Problem constants (from reference): B=2048, T=128, A=8, D=64, H=128
#define BT   (2048 * 128)   // positions
#define NA   8              // actions
#define DD   64             // embedding dim
#define HH   128            // hidden dim
#define EDGE_STRIDE (9 * DD) // (1+A)*D floats per position in edge tensors

__device__ __forceinline__ float softplus_f(float x) {
    // numerically-stable softplus: max(x,0) + log1p(exp(-|x|))
    return fmaxf(x, 0.0f) + log1pf(expf(-fabsf(x)));
}

__global__ __launch_bounds__(256)
void gflow_kernel(const float* __restrict__ fwd,       // [B,T,9,64]
                  const float* __restrict__ bwd,       // [B,T,9,64]
                  const float* __restrict__ reward,    // [B,T]
                  const float* __restrict__ init_flow, // [1]
                  const float* __restrict__ W1,        // [64,128] row-major
                  const float* __restrict__ b1,        // [128]
                  const float* __restrict__ W2,        // [128,8] row-major
                  const float* __restrict__ b2,        // [8]
                  float* __restrict__ out)             // [B,T,2]
{
    const int pos = blockIdx.x * blockDim.x + threadIdx.x;
    if (pos >= BT) return;

    float xr[DD];

    // ---------------- Forward state: need all 8 outputs ----------------
    {
        const float* x = fwd + (size_t)pos * EDGE_STRIDE; // edge 0
        #pragma unroll
        for (int i = 0; i < DD / 4; ++i) {
            float4 v = ((const float4*)x)[i];
            xr[4*i+0] = v.x; xr[4*i+1] = v.y; xr[4*i+2] = v.z; xr[4*i+3] = v.w;
        }
        float logit[NA];
        #pragma unroll
        for (int k = 0; k < NA; ++k) logit[k] = b2[k];

        for (int jb = 0; jb < HH / 16; ++jb) {
            float hc[16];
            #pragma unroll
            for (int jj = 0; jj < 16; ++jj) hc[jj] = b1[jb*16 + jj];
            #pragma unroll 4
            for (int i = 0; i < DD; ++i) {
                const float xi = xr[i];
                #pragma unroll
                for (int jj = 0; jj < 16; ++jj)
                    hc[jj] = fmaf(xi, W1[i*HH + jb*16 + jj], hc[jj]);
            }
            #pragma unroll
            for (int jj = 0; jj < 16; ++jj) {
                const float h = fmaxf(hc[jj], 0.0f);
                #pragma unroll
                for (int k = 0; k < NA; ++k)
                    logit[k] = fmaf(h, W2[(jb*16 + jj)*NA + k], logit[k]);
            }
        }
        float s = 0.0f;
        #pragma unroll
        for (int k = 0; k < NA; ++k) s += softplus_f(logit[k]);
        out[2*(size_t)pos + 1] = s + reward[pos];
    }

    // ---------------- Backward edges 1..8: need only output e-1 ----------------
    float fin = 0.0f;
    for (int e = 0; e < NA; ++e) {   // backward edge index e+1, output column e
        const float* x = bwd + (size_t)pos * EDGE_STRIDE + (size_t)(e + 1) * DD;
        #pragma unroll
        for (int i = 0; i < DD / 4; ++i) {
            float4 v = ((const float4*)x)[i];
            xr[4*i+0] = v.x; xr[4*i+1] = v.y; xr[4*i+2] = v.z; xr[4*i+3] = v.w;
        }
        float logit = b2[e];
        for (int jb = 0; jb < HH / 16; ++jb) {
            float hc[16];
            #pragma unroll
            for (int jj = 0; jj < 16; ++jj) hc[jj] = b1[jb*16 + jj];
            #pragma unroll 4
            for (int i = 0; i < DD; ++i) {
                const float xi = xr[i];
                #pragma unroll
                for (int jj = 0; jj < 16; ++jj)
                    hc[jj] = fmaf(xi, W1[i*HH + jb*16 + jj], hc[jj]);
            }
            #pragma unroll
            for (int jj = 0; jj < 16; ++jj)
                logit = fmaf(fmaxf(hc[jj], 0.0f), W2[(jb*16 + jj)*NA + e], logit);
        }
        fin += softplus_f(logit);
    }
    out[2*(size_t)pos] = init_flow[0] + fin;
}

extern "C" void kernel_launch(void* const* d_in, const int* in_sizes, int n_in,
                              void* d_out, int out_size, void* d_ws, size_t ws_size,
                              hipStream_t stream) {
    const float* fwd       = (const float*)d_in[0];
    const float* bwd       = (const float*)d_in[1];
    const float* reward    = (const float*)d_in[2];
    const float* init_flow = (const float*)d_in[3];
    const float* W1        = (const float*)d_in[4];
    const float* b1        = (const float*)d_in[5];
    const float* W2        = (const float*)d_in[6];
    const float* b2        = (const float*)d_in[7];
    float* out             = (float*)d_out;

    dim3 grid(BT / 256), block(256);
    hipLaunchKernelGGL(gflow_kernel, grid, block, 0, stream,
                       fwd, bwd, reward, init_flow, W1, b1, W2, b2, out);
}